// Round 12
// baseline (34.058 us; speedup 1.0000x reference)
//
#include <hip/hip_runtime.h>

// Reference collapses: softmax over singleton axis == 1 =>
//   out[b,c,:,:] = (Wout @ v_b + bout)[c],  v_b = Wkv[C:,:] @ context[b]
// x, Wq dead. Bound by the 134 MB output write.
//
// R12 theory: our splat stores run ~5 TB/s vs fill's 7.1 because each wave
// owned a private 16 KB row -> ~2K scattered write streams -> DRAM page
// thrash. Fix: bcast is a FILL-CLONE — grid-stride linear sweep, the row
// index (k*2048+w)>>4 is wave-uniform -> y via s_load from a 32 KB L2-hot
// table. 3 kernels: v, y, sweep-bcast.

#define BB   16
#define CC   512
#define CTX  256
#define NN   4096   // H*W

typedef float f32x4 __attribute__((ext_vector_type(4)));

// K1: v[b*C+j] = dot(Wkv[C+j,:], ctx[b,:]).  One wave per (b,j).
__global__ __launch_bounds__(256) void v_kernel(
    const float* __restrict__ ctx,   // B x CTX
    const float* __restrict__ Wkv,   // 2C x CTX
    float* __restrict__ v)           // B*C
{
    const int w    = (blockIdx.x << 2) + (threadIdx.x >> 6);  // 0..8191
    const int lane = threadIdx.x & 63;
    const int b    = w >> 9;
    const int j    = w & (CC - 1);

    const f32x4 cx = ((const f32x4*)(ctx + b * CTX))[lane];
    const f32x4 wv = ((const f32x4*)(Wkv + (size_t)(CC + j) * CTX))[lane];
    float p = wv.x * cx.x + wv.y * cx.y + wv.z * cx.z + wv.w * cx.w;
    #pragma unroll
    for (int m = 32; m >= 1; m >>= 1) p += __shfl_xor(p, m);
    if (lane == 0) v[w] = p;
}

// K1b: y[b*C+c] = dot(Wout[c,:], v[b,:]) + bout[c].  One wave per (b,c).
__global__ __launch_bounds__(256) void y_kernel(
    const float* __restrict__ v,     // B*C
    const float* __restrict__ Wout,  // C x C
    const float* __restrict__ bout,  // C
    float* __restrict__ y)           // B*C
{
    const int w    = (blockIdx.x << 2) + (threadIdx.x >> 6);
    const int lane = threadIdx.x & 63;
    const int b    = w >> 9;
    const int c    = w & (CC - 1);

    const f32x4* vr = (const f32x4*)(v + (size_t)b * CC);
    const f32x4* wr = (const f32x4*)(Wout + (size_t)c * CC);
    const f32x4 w0 = wr[lane],      v0 = vr[lane];
    const f32x4 w1 = wr[64 + lane], v1 = vr[64 + lane];
    float p = w0.x * v0.x + w0.y * v0.y + w0.z * v0.z + w0.w * v0.w
            + w1.x * v1.x + w1.y * v1.y + w1.z * v1.z + w1.w * v1.w;
    #pragma unroll
    for (int m = 32; m >= 1; m >>= 1) p += __shfl_xor(p, m);
    if (lane == 0) y[w] = p + bout[c];
}

// K2: fill-clone broadcast. 512 blocks x 256 thr = 2048 waves; iteration k,
// wave w stores the contiguous 1 KB window at f32x4 index (k*2048+w)*64.
// Whole grid sweeps memory linearly like the 7.1 TB/s fill kernel.
// Row = (k*2048+w)>>4 is wave-uniform -> one s_load/iter from 32 KB y-table.
__global__ __launch_bounds__(256) void bcast_kernel(
    const float* __restrict__ y, f32x4* __restrict__ out)
{
    const int wid  = __builtin_amdgcn_readfirstlane((blockIdx.x << 2) + (threadIdx.x >> 6));
    const int lane = threadIdx.x & 63;

    f32x4* dst = out + (size_t)wid * 64 + lane;
    int rowkey  = wid;                      // row = rowkey >> 4
    float yv    = y[rowkey >> 4];

    #pragma unroll 4
    for (int it = 0; it < 64; ++it) {
        const float yn = (it < 63) ? y[(rowkey + 2048) >> 4] : 0.f;  // prefetch
        f32x4 val; val.x = yv; val.y = yv; val.z = yv; val.w = yv;
        *dst = val;
        dst += 131072;                      // 2 MB / 16 B: whole-grid stride
        rowkey += 2048;
        yv = yn;
    }
}

extern "C" void kernel_launch(void* const* d_in, const int* in_sizes, int n_in,
                              void* d_out, int out_size, void* d_ws, size_t ws_size,
                              hipStream_t stream) {
    // inputs: 0=x (dead), 1=context, 2=Wq (dead), 3=Wkv, 4=Wout, 5=bout
    const float* context = (const float*)d_in[1];
    const float* Wkv     = (const float*)d_in[3];
    const float* Wout    = (const float*)d_in[4];
    const float* bout    = (const float*)d_in[5];
    f32x4* out = (f32x4*)d_out;

    float* y = (float*)d_ws;                 // 32 KB  (bcast reads this)
    float* v = (float*)d_ws + BB * CC;       // 32 KB

    v_kernel<<<2048, 256, 0, stream>>>(context, Wkv, v);
    y_kernel<<<2048, 256, 0, stream>>>(v, Wout, bout, y);
    bcast_kernel<<<512, 256, 0, stream>>>(y, out);
}

// Round 13
// 30.747 us; speedup vs baseline: 1.1077x; 1.1077x over previous
//
#include <hip/hip_runtime.h>

// Reference collapses: softmax over singleton axis == 1 =>
//   out[b,c,:,:] = (Wout @ v_b + bout)[c],  v_b = Wkv[C:,:] @ context[b]
// x, Wq dead. Bound by: 134 MB store (~19 us @ 7 TB/s) + ~4 us/graph-node.
// Ledger (R4-R12 fit): 2 nodes minimum (bilinear dep needs one staging
// point; all in-kernel sync forms cost 13-50 us > a boundary's 4).
// R13: R11 structure, K2 preamble software-pipelined with the store stream.

#define BB   16
#define CC   512
#define CTX  256
#define NN   4096   // H*W

typedef float f32x4 __attribute__((ext_vector_type(4)));

// K1: v[b*C+j] = dot(Wkv[C+j,:], ctx[b,:]).  One wave per (b,j).
__global__ __launch_bounds__(256) void v_kernel(
    const float* __restrict__ ctx,   // B x CTX
    const float* __restrict__ Wkv,   // 2C x CTX
    float* __restrict__ v)           // B*C (d_ws)
{
    const int w    = (blockIdx.x << 2) + (threadIdx.x >> 6);  // 0..8191
    const int lane = threadIdx.x & 63;
    const int b    = w >> 9;
    const int j    = w & (CC - 1);

    const f32x4 cx = ((const f32x4*)(ctx + b * CTX))[lane];
    const f32x4 wv = ((const f32x4*)(Wkv + (size_t)(CC + j) * CTX))[lane];
    float p = wv.x * cx.x + wv.y * cx.y + wv.z * cx.z + wv.w * cx.w;
    #pragma unroll
    for (int m = 32; m >= 1; m >>= 1) p += __shfl_xor(p, m);
    if (lane == 0) v[w] = p;
}

// K2: block = channel c (512 blocks, 4 waves); wave = 4 batches.
// Wout[c,:] read once per block (L1-deduped across its waves). All v rows
// hoisted (independent loads -> ILP), then per-batch {butterfly; 16 stores}
// so stores of batch i overlap the reduce of batch i+1.
__global__ __launch_bounds__(256) void out_kernel(
    const float* __restrict__ v,     // B*C (32 KB, L2-hot)
    const float* __restrict__ Wout,  // C x C
    const float* __restrict__ bout,  // C
    f32x4* __restrict__ out)
{
    const int c    = blockIdx.x;                 // 0..511
    const int wave = threadIdx.x >> 6;           // 0..3
    const int lane = threadIdx.x & 63;
    const int b0   = wave << 2;                  // 4 batches per wave

    const f32x4* wr = (const f32x4*)(Wout + (size_t)c * CC);
    const f32x4 w0 = wr[lane], w1 = wr[64 + lane];
    const float bb = bout[c];

    // hoist all v loads: 8 independent f32x4 (ILP hides L2 latency)
    f32x4 v0[4], v1[4];
    #pragma unroll
    for (int i = 0; i < 4; ++i) {
        const f32x4* vr = (const f32x4*)(v + (size_t)(b0 + i) * CC);
        v0[i] = vr[lane];
        v1[i] = vr[64 + lane];
    }

    #pragma unroll
    for (int i = 0; i < 4; ++i) {
        float p = w0.x * v0[i].x + w0.y * v0[i].y + w0.z * v0[i].z + w0.w * v0[i].w
                + w1.x * v1[i].x + w1.y * v1[i].y + w1.z * v1[i].z + w1.w * v1[i].w;
        #pragma unroll
        for (int m = 32; m >= 1; m >>= 1) p += __shfl_xor(p, m);
        const float y = p + bb;

        f32x4 val; val.x = y; val.y = y; val.z = y; val.w = y;
        f32x4* dst = out + (size_t)(((b0 + i) << 9) + c) * (NN / 4) + lane;
        #pragma unroll
        for (int j = 0; j < 16; ++j)
            dst[j * 64] = val;
    }
}

extern "C" void kernel_launch(void* const* d_in, const int* in_sizes, int n_in,
                              void* d_out, int out_size, void* d_ws, size_t ws_size,
                              hipStream_t stream) {
    // inputs: 0=x (dead), 1=context, 2=Wq (dead), 3=Wkv, 4=Wout, 5=bout
    const float* context = (const float*)d_in[1];
    const float* Wkv     = (const float*)d_in[3];
    const float* Wout    = (const float*)d_in[4];
    const float* bout    = (const float*)d_in[5];
    f32x4* out = (f32x4*)d_out;
    float* v   = (float*)d_ws;   // 32 KB

    v_kernel<<<2048, 256, 0, stream>>>(context, Wkv, v);
    out_kernel<<<512, 256, 0, stream>>>(v, Wout, bout, out);
}